// Round 16
// baseline (1819.281 us; speedup 1.0000x reference)
//
#include <hip/hip_runtime.h>
#include <hip/hip_bf16.h>
#include <math.h>

namespace {
constexpr int NL  = 2;          // layers
constexpr int H   = 2048;
constexpr int NH  = 16;
constexpr int NKV = 2;
constexpr int HD  = 128;
constexpr int FF  = 11008;
constexpr int BB  = 32;         // batch
constexpr int SS  = 64;         // seq
constexpr int RR  = 16;         // lora rank
constexpr int TT  = BB * SS;    // 2048 tokens
constexpr int KVD = NKV * HD;   // 256
constexpr int QKVD = H + 2 * KVD; // 2560 fused qkv width
constexpr int PH  = 1024, TDm = 512;
constexpr float LSCALE = 2.0f;  // lora alpha/r
}

typedef __bf16 bf16x8 __attribute__((ext_vector_type(8)));
typedef float  f32x4  __attribute__((ext_vector_type(4)));

__device__ __forceinline__ ushort4 f4_to_bf4(float4 r) {
  __hip_bfloat16 a = __float2bfloat16(r.x), b = __float2bfloat16(r.y),
                 c = __float2bfloat16(r.z), d = __float2bfloat16(r.w);
  return make_ushort4(*(unsigned short*)&a, *(unsigned short*)&b,
                      *(unsigned short*)&c, *(unsigned short*)&d);
}

__device__ __forceinline__ bf16x8 f8cvt(float4 a, float4 b) {
  bf16x8 r;
  r[0] = (__bf16)a.x; r[1] = (__bf16)a.y; r[2] = (__bf16)a.z; r[3] = (__bf16)a.w;
  r[4] = (__bf16)b.x; r[5] = (__bf16)b.y; r[6] = (__bf16)b.z; r[7] = (__bf16)b.w;
  return r;
}

__device__ __forceinline__ float dot4(float4 a, float4 b) {
  return a.x * b.x + a.y * b.y + a.z * b.z + a.w * b.w;
}

// ---------------- embedding gather ----------------
__global__ __launch_bounds__(256) void k_embed(const int* __restrict__ ids,
                                               const float* __restrict__ emb,
                                               float* __restrict__ h) {
  int t = blockIdx.x;
  long id = ids[t];
  const float4* src = reinterpret_cast<const float4*>(emb + id * (long)H);
  float4* dst = reinterpret_cast<float4*>(h + (long)t * H);
  for (int i = threadIdx.x; i < H / 4; i += 256) dst[i] = src[i];
}

// ---------------- fp32 -> bf16 converts ----------------
__global__ __launch_bounds__(256) void k_cvt(const float* __restrict__ src,
                                             __hip_bfloat16* __restrict__ dst, long n) {
  long i = ((long)blockIdx.x * 256 + threadIdx.x) * 4;
  if (i >= n) return;
  float4 v = *reinterpret_cast<const float4*>(src + i);
  *reinterpret_cast<ushort4*>(dst + i) = f4_to_bf4(v);
}

// QKV concat convert (3 sources -> one dst) — one dispatch per layer
__global__ __launch_bounds__(256) void k_cvt_qkv(
    const float* __restrict__ Wq, const float* __restrict__ Wk,
    const float* __restrict__ Wv, __hip_bfloat16* __restrict__ dst) {
  long i = ((long)blockIdx.x * 256 + threadIdx.x) * 4;
  const long n1 = (long)H * H, n2 = n1 + (long)KVD * H, nt = (long)QKVD * H;
  if (i >= nt) return;
  const float* src; long off;
  if (i < n1)      { src = Wq; off = i; }
  else if (i < n2) { src = Wk; off = i - n1; }
  else             { src = Wv; off = i - n2; }
  float4 v = *reinterpret_cast<const float4*>(src + off);
  *reinterpret_cast<ushort4*>(dst + i) = f4_to_bf4(v);
}

// Wg/Wu/Wd convert (3 equal regions, contiguous dsts) — one dispatch
__global__ __launch_bounds__(256) void k_cvt3(
    const float* __restrict__ s0, const float* __restrict__ s1,
    const float* __restrict__ s2, __hip_bfloat16* __restrict__ dst) {
  long i = ((long)blockIdx.x * 256 + threadIdx.x) * 4;
  const long n = (long)FF * H;
  if (i >= 3 * n) return;
  const float* src; long off;
  if (i < n)          { src = s0; off = i; }
  else if (i < 2 * n) { src = s1; off = i - n; }
  else                { src = s2; off = i - 2 * n; }
  float4 v = *reinterpret_cast<const float4*>(src + off);
  *reinterpret_cast<ushort4*>(dst + i) = f4_to_bf4(v);
}

// ---------------- prep: biascat + Bcat for both layers ----------------
__global__ __launch_bounds__(256) void k_prep(
    const float* __restrict__ bq, const float* __restrict__ bk, const float* __restrict__ bv,
    const float* __restrict__ Bq, const float* __restrict__ Bk, const float* __restrict__ Bv,
    float* __restrict__ biascat, float* __restrict__ bcat) {
  int idx = blockIdx.x * 256 + threadIdx.x;   // l*QKVD + col
  if (idx >= NL * QKVD) return;
  int l = idx / QKVD, col = idx % QKVD;
  const float* bsrc; const float* Bsrc;
  if (col < H)            { bsrc = bq + (long)l * H + col;            Bsrc = Bq + ((long)l * H + col) * RR; }
  else if (col < H + KVD) { bsrc = bk + (long)l * KVD + (col - H);    Bsrc = Bk + ((long)l * KVD + col - H) * RR; }
  else                    { bsrc = bv + (long)l * KVD + (col - H - KVD); Bsrc = Bv + ((long)l * KVD + col - H - KVD) * RR; }
  biascat[idx] = *bsrc;
  #pragma unroll
  for (int r = 0; r < RR; ++r) bcat[(long)idx * RR + r] = Bsrc[r];
}

// ---------------- rmsnorm (block per token), dual fp32+bf16 out -----------
__global__ __launch_bounds__(256) void k_rmsnorm(const float* __restrict__ in,
                                                 const float* __restrict__ w,
                                                 float* __restrict__ out,
                                                 __hip_bfloat16* __restrict__ outb) {
  int t = blockIdx.x, tid = threadIdx.x;
  const float4* xr = reinterpret_cast<const float4*>(in + (long)t * H);
  float4 v0 = xr[tid], v1 = xr[tid + 256];
  float ss = v0.x*v0.x + v0.y*v0.y + v0.z*v0.z + v0.w*v0.w
           + v1.x*v1.x + v1.y*v1.y + v1.z*v1.z + v1.w*v1.w;
  #pragma unroll
  for (int off = 32; off; off >>= 1) ss += __shfl_xor(ss, off);
  __shared__ float sred[4];
  if ((tid & 63) == 0) sred[tid >> 6] = ss;
  __syncthreads();
  float scale = rsqrtf((sred[0] + sred[1] + sred[2] + sred[3]) * (1.0f / H) + 1e-6f);
  const float4* wr = reinterpret_cast<const float4*>(w);
  float4 w0 = wr[tid], w1 = wr[tid + 256];
  float4 r0 = make_float4(v0.x*scale*w0.x, v0.y*scale*w0.y, v0.z*scale*w0.z, v0.w*scale*w0.w);
  float4 r1 = make_float4(v1.x*scale*w1.x, v1.y*scale*w1.y, v1.z*scale*w1.z, v1.w*scale*w1.w);
  float4* o = reinterpret_cast<float4*>(out + (long)t * H);
  o[tid] = r0; o[tid + 256] = r1;
  ushort4* ob = reinterpret_cast<ushort4*>(outb + (long)t * H);
  ob[tid] = f4_to_bf4(r0); ob[tid + 256] = f4_to_bf4(r1);
}

// ===================== MFMA bf16 GEMM, fused LoRA ==========================
// 512 thr / 8 waves, per-wave 64x16 (FM=4, FN=1) — r15 TLP lesson applied:
// same BM=64/BN=128/BK=64 tile + 48KB LDS (2 blocks/CU), double the resident
// waves/SIMD to hide the per-K-step drain. acc = 16 VGPR.
enum { ME_BIAS_F32 = 0, ME_ACC_F32 = 1 };

__device__ __forceinline__ int raster_sw(int bid, int nwg) {
  // bijective XCD remap (m204)
  int q8 = nwg >> 3, r8 = nwg & 7;
  int xcd = bid & 7, pos = bid >> 3;
  return (xcd < r8 ? xcd * (q8 + 1) : r8 * (q8 + 1) + (xcd - r8) * q8) + pos;
}

template <int EPI, bool LORA, bool WBF16>
__global__ __launch_bounds__(512, 1) void k_mgemm(
    const __hip_bfloat16* __restrict__ Abf,
    const float* __restrict__ W0, const float* __restrict__ W1, const float* __restrict__ W2,
    const __hip_bfloat16* __restrict__ Wb,
    const float* __restrict__ bias,
    float* __restrict__ Cf,
    const float* __restrict__ lt, const float* __restrict__ lB, int ltStride,
    int qkvMode, int M, int N, int K) {
  constexpr int BM = 64, BN = 128, BK = 64;
  constexpr int FM = 4, FN = 1;            // per-wave 64x16
  __shared__ __align__(16) __bf16 As[2][BM * BK];   // 8 KB x2
  __shared__ __align__(16) __bf16 Bs[2][BN * BK];   // 16 KB x2
  const int tid = threadIdx.x;
  const int sw = raster_sw(blockIdx.x, gridDim.x);
  const int ntm = M / BM;
  const int bm = (sw % ntm) * BM, bn = (sw / ntm) * BN;   // col-major raster
  const int lane = tid & 63, wid = tid >> 6;              // 8 waves
  const int wn = wid * 16;
  const int lr15 = lane & 15;
  const int g4 = lane >> 4;                               // k-chunk group 0..3
  f32x4 acc[FM][FN] = {};
  const __bf16* Ag = reinterpret_cast<const __bf16*>(Abf) + (long)bm * K;

  const float* Wsrc = W0; int wrow0 = bn;
  if constexpr (!WBF16) {
    if (qkvMode) {
      if (bn >= H + KVD)      { Wsrc = W2; wrow0 = bn - (H + KVD); }
      else if (bn >= H)       { Wsrc = W1; wrow0 = bn - H; }
    }
  }
  const __bf16* Wg16 = reinterpret_cast<const __bf16*>(Wb) + (long)bn * K;

  // A: 512 chunks = 1/thread (64 rows x 8 chunk-cols)
  const int arow = tid >> 3, acol = tid & 7;

  auto stageA = [&](int buf, int k0) {
    __builtin_amdgcn_global_load_lds(
        (const __attribute__((address_space(1))) void*)
          (Ag + (long)arow * K + k0 + ((acol ^ (arow & 7)) << 3)),
        (__attribute__((address_space(3))) void*)(&As[buf][tid * 8]), 16, 0, 0);
  };

  // B: 1024 chunks = 2/thread
  auto stageB16 = [&](int buf, int k0) {
    #pragma unroll
    for (int q = 0; q < 2; ++q) {
      int c = tid + q * 512;
      int row = c >> 3, col = c & 7;
      __builtin_amdgcn_global_load_lds(
          (const __attribute__((address_space(1))) void*)
            (Wg16 + (long)row * K + k0 + ((col ^ (row & 7)) << 3)),
          (__attribute__((address_space(3))) void*)(&Bs[buf][c * 8]), 16, 0, 0);
    }
  };

  float4 bb[2][2];
  auto loadB = [&](int k0) {
    #pragma unroll
    for (int q = 0; q < 2; ++q) {
      int c = tid + q * 512;
      int r = c >> 3, col = c & 7;
      const float* p = Wsrc + (long)(wrow0 + r) * K + k0 + ((col ^ (r & 7)) << 3);
      bb[q][0] = *reinterpret_cast<const float4*>(p);
      bb[q][1] = *reinterpret_cast<const float4*>(p + 4);
    }
  };
  auto writeB = [&](int buf) {
    #pragma unroll
    for (int q = 0; q < 2; ++q)
      *reinterpret_cast<bf16x8*>(&Bs[buf][(tid + q * 512) * 8]) = f8cvt(bb[q][0], bb[q][1]);
  };

  auto compute = [&](int buf) {
    #pragma unroll
    for (int ks = 0; ks < 2; ++ks) {
      bf16x8 af[FM], bfr[FN];
      #pragma unroll
      for (int m = 0; m < FM; ++m) {
        int row = m * 16 + lr15;
        af[m] = *reinterpret_cast<const bf16x8*>(
            &As[buf][row * BK + (((g4 + 4 * ks) ^ (row & 7)) << 3)]);
      }
      #pragma unroll
      for (int n = 0; n < FN; ++n) {
        int row = wn + n * 16 + lr15;
        bfr[n] = *reinterpret_cast<const bf16x8*>(
            &Bs[buf][row * BK + (((g4 + 4 * ks) ^ (row & 7)) << 3)]);
      }
      #pragma unroll
      for (int m = 0; m < FM; ++m)
        #pragma unroll
        for (int n = 0; n < FN; ++n)
          acc[m][n] = __builtin_amdgcn_mfma_f32_16x16x32_bf16(af[m], bfr[n], acc[m][n], 0, 0, 0);
    }
  };

  const int NS = K / BK;
  if constexpr (WBF16) {
    stageA(0, 0); stageB16(0, 0);
    __syncthreads();
    int cur = 0;
    for (int t = 0; t < NS; ++t) {
      if (t + 1 < NS) { stageA(cur ^ 1, (t + 1) * BK); stageB16(cur ^ 1, (t + 1) * BK); }
      compute(cur);
      if (t + 1 < NS) { __syncthreads(); cur ^= 1; }
    }
  } else {
    loadB(0);
    stageA(0, 0);
    writeB(0);
    __syncthreads();
    int cur = 0;
    for (int t = 0; t < NS; ++t) {
      if (t + 1 < NS) { loadB((t + 1) * BK); stageA(cur ^ 1, (t + 1) * BK); }
      compute(cur);
      if (t + 1 < NS) {
        writeB(cur ^ 1);
        __syncthreads();
        cur ^= 1;
      }
    }
  }

  // ---- epilogue: bias / accumulate, optional fused LoRA ----
  const int r0 = g4 << 2;
  float4 lb[FN][4];
  int goff = 0;
  if constexpr (LORA) {
    if (qkvMode) goff = (bn >= H + KVD) ? 32 : (bn >= H ? 16 : 0);
    #pragma unroll
    for (int n = 0; n < FN; ++n) {
      const float4* p = reinterpret_cast<const float4*>(lB + (long)(bn + wn + n * 16 + lr15) * RR);
      lb[n][0] = p[0]; lb[n][1] = p[1]; lb[n][2] = p[2]; lb[n][3] = p[3];
    }
  }
  float bcol[FN];
  if constexpr (EPI == ME_BIAS_F32) {
    #pragma unroll
    for (int n = 0; n < FN; ++n) bcol[n] = bias[bn + wn + n * 16 + lr15];
  }
  #pragma unroll
  for (int m = 0; m < FM; ++m)
    #pragma unroll
    for (int j = 0; j < 4; ++j) {
      const long row = bm + m * 16 + r0 + j;
      float lv[FN];
      if constexpr (LORA) {
        const float4* tp = reinterpret_cast<const float4*>(lt + row * ltStride + goff);
        float4 t0 = tp[0], t1 = tp[1], t2 = tp[2], t3 = tp[3];
        #pragma unroll
        for (int n = 0; n < FN; ++n)
          lv[n] = LSCALE * (dot4(t0, lb[n][0]) + dot4(t1, lb[n][1]) +
                            dot4(t2, lb[n][2]) + dot4(t3, lb[n][3]));
      }
      #pragma unroll
      for (int n = 0; n < FN; ++n) {
        const int col = bn + wn + n * 16 + lr15;
        float v = acc[m][n][j];
        if constexpr (LORA) v += lv[n];
        if constexpr (EPI == ME_BIAS_F32) Cf[row * N + col] = v + bcol[n];
        else                              Cf[row * N + col] += v;
      }
    }
}

// ------ fused SwiGLU, bf16 weights, 512 thr / 8 waves (r15: 238us) ---------
// 128x128 tile + BK=32 + 48KB LDS; 8 waves (2x4) each 64x32 (FM=4,FN=2).
// Occupancy 38.6%, MfmaUtil 33.7% — keep exactly.
__global__ __launch_bounds__(512, 1) void k_swiglu_b(
    const __hip_bfloat16* __restrict__ Abf,
    const __hip_bfloat16* __restrict__ Wgb,
    const __hip_bfloat16* __restrict__ Wub,
    __hip_bfloat16* __restrict__ Cb,
    int M, int N, int K) {
  constexpr int BM = 128, BN = 128, BK = 32;
  constexpr int FM = 4, FN = 2;
  __shared__ __align__(16) __bf16 As[2][BM * BK];
  __shared__ __align__(16) __bf16 Gs[2][BN * BK];
  __shared__ __align__(16) __bf16 Us[2][BN * BK];
  const int tid = threadIdx.x;
  const int sw = raster_sw(blockIdx.x, gridDim.x);
  const int ntm = M / BM;
  const int bm = (sw % ntm) * BM, bn = (sw / ntm) * BN;
  const int lane = tid & 63, wid = tid >> 6;            // 8 waves (2x4)
  const int wm = (wid >> 2) * 64, wn = (wid & 3) * 32;
  const int lr15 = lane & 15;
  const int lks = (((lane >> 4) << 3)) ^ ((((lr15 >> 1) & 3)) << 3);
  f32x4 accg[FM][FN] = {}, accu[FM][FN] = {};
  const __bf16* Ag = reinterpret_cast<const __bf16*>(Abf) + (long)bm * K;
  const __bf16* Gg = reinterpret_cast<const __bf16*>(Wgb) + (long)bn * K;
  const __bf16* Ug = reinterpret_cast<const __bf16*>(Wub) + (long)bn * K;

  auto stage = [&](int buf, int k0) {
    const int i = tid;   // 512 threads cover 512 chunks/operand
    const int sc = ((i & 3) ^ ((i >> 3) & 3)) << 3;
    const long ro = (long)(i >> 2) * K + k0 + sc;
    __builtin_amdgcn_global_load_lds(
        (const __attribute__((address_space(1))) void*)(Ag + ro),
        (__attribute__((address_space(3))) void*)(&As[buf][i * 8]), 16, 0, 0);
    __builtin_amdgcn_global_load_lds(
        (const __attribute__((address_space(1))) void*)(Gg + ro),
        (__attribute__((address_space(3))) void*)(&Gs[buf][i * 8]), 16, 0, 0);
    __builtin_amdgcn_global_load_lds(
        (const __attribute__((address_space(1))) void*)(Ug + ro),
        (__attribute__((address_space(3))) void*)(&Us[buf][i * 8]), 16, 0, 0);
  };
  auto compute = [&](int buf) {
    bf16x8 af[FM], gf[FN], uf[FN];
    #pragma unroll
    for (int m = 0; m < FM; ++m)
      af[m] = *reinterpret_cast<const bf16x8*>(&As[buf][(wm + m * 16 + lr15) * BK + lks]);
    #pragma unroll
    for (int n = 0; n < FN; ++n) {
      gf[n] = *reinterpret_cast<const bf16x8*>(&Gs[buf][(wn + n * 16 + lr15) * BK + lks]);
      uf[n] = *reinterpret_cast<const bf16x8*>(&Us[buf][(wn + n * 16 + lr15) * BK + lks]);
    }
    #pragma unroll
    for (int m = 0; m < FM; ++m)
      #pragma unroll
      for (int n = 0; n < FN; ++n) {
        accg[m][n] = __builtin_amdgcn_mfma_f32_16x16x32_bf16(af[m], gf[n], accg[m][n], 0, 0, 0);
        accu[m][n] = __builtin_amdgcn_mfma_f32_16x16x32_bf16(af[m], uf[n], accu[m][n], 0, 0, 0);
      }
  };

  const int NS = K / BK;
  stage(0, 0);
  asm volatile("s_waitcnt vmcnt(0)" ::: "memory");
  __builtin_amdgcn_s_barrier();
  int cur = 0;
  for (int t = 0; t < NS; ++t) {
    if (t + 1 < NS) stage(cur ^ 1, (t + 1) * BK);
    compute(cur);
    if (t + 1 < NS) {
      asm volatile("s_waitcnt vmcnt(0)" ::: "memory");
      __builtin_amdgcn_s_barrier();
      cur ^= 1;
    }
  }

  const int r0 = (lane >> 4) << 2;
  #pragma unroll
  for (int m = 0; m < FM; ++m)
    #pragma unroll
    for (int n = 0; n < FN; ++n) {
      const int col = bn + wn + n * 16 + lr15;
      const long rowb = bm + wm + m * 16 + r0;
      #pragma unroll
      for (int j = 0; j < 4; ++j) {
        float g = accg[m][n][j], u = accu[m][n][j];
        Cb[(rowb + j) * N + col] = __float2bfloat16((g / (1.0f + expf(-g))) * u);
      }
    }
}

// ------------- fallback fused SwiGLU (fp32-direct weights, r9) -------------
__global__ __launch_bounds__(256, 2) void k_swiglu(
    const __hip_bfloat16* __restrict__ Abf,
    const float* __restrict__ Wg,
    const float* __restrict__ Wu,
    __hip_bfloat16* __restrict__ Cb,
    int M, int N, int K) {
  constexpr int BM = 128, BN = 128, BK = 32;
  constexpr int FM = 4, FN = 4;
  __shared__ __align__(16) __bf16 As[2][BM * BK];
  __shared__ __align__(16) __bf16 Gs[2][BN * BK];
  __shared__ __align__(16) __bf16 Us[2][BN * BK];
  const int tid = threadIdx.x;
  const int sw = raster_sw(blockIdx.x, gridDim.x);
  const int ntm = M / BM;
  const int bm = (sw % ntm) * BM, bn = (sw / ntm) * BN;
  const int lane = tid & 63, wv = tid >> 6;
  const int wm = (wv >> 1) * 64, wn = (wv & 1) * 64;
  const int lr15 = lane & 15;
  const int lks = (((lane >> 4) << 3)) ^ ((((lr15 >> 1) & 3)) << 3);
  f32x4 accg[FM][FN] = {}, accu[FM][FN] = {};
  const __bf16* Ag = reinterpret_cast<const __bf16*>(Abf) + (long)bm * K;

  const int br0 = tid >> 2, bc = tid & 3;
  const int br1 = br0 + 64;
  const float* gp0 = Wg + (long)(bn + br0) * K + bc * 8;
  const float* gp1 = Wg + (long)(bn + br1) * K + bc * 8;
  const float* up0 = Wu + (long)(bn + br0) * K + bc * 8;
  const float* up1 = Wu + (long)(bn + br1) * K + bc * 8;
  const int d0 = br0 * BK + ((bc ^ ((br0 >> 1) & 3)) << 3);
  const int d1 = br1 * BK + ((bc ^ ((br1 >> 1) & 3)) << 3);

  float4 g00, g01, g10, g11, u00, u01, u10, u11;
  auto loadB = [&](int k0) {
    g00 = *reinterpret_cast<const float4*>(gp0 + k0);
    g01 = *reinterpret_cast<const float4*>(gp0 + k0 + 4);
    g10 = *reinterpret_cast<const float4*>(gp1 + k0);
    g11 = *reinterpret_cast<const float4*>(gp1 + k0 + 4);
    u00 = *reinterpret_cast<const float4*>(up0 + k0);
    u01 = *reinterpret_cast<const float4*>(up0 + k0 + 4);
    u10 = *reinterpret_cast<const float4*>(up1 + k0);
    u11 = *reinterpret_cast<const float4*>(up1 + k0 + 4);
  };
  auto writeB = [&](int buf) {
    *reinterpret_cast<bf16x8*>(&Gs[buf][d0]) = f8cvt(g00, g01);
    *reinterpret_cast<bf16x8*>(&Gs[buf][d1]) = f8cvt(g10, g11);
    *reinterpret_cast<bf16x8*>(&Us[buf][d0]) = f8cvt(u00, u01);
    *reinterpret_cast<bf16x8*>(&Us[buf][d1]) = f8cvt(u10, u11);
  };
  auto stageA = [&](int buf, int k0) {
    #pragma unroll
    for (int i = tid; i < BM * BK / 8; i += 256)
      __builtin_amdgcn_global_load_lds(
          (const __attribute__((address_space(1))) void*)
            (Ag + (long)(i >> 2) * K + k0 + (((i & 3) ^ ((i >> 3) & 3)) << 3)),
          (__attribute__((address_space(3))) void*)(&As[buf][i * 8]), 16, 0, 0);
  };
  auto compute = [&](int buf) {
    bf16x8 af[FM], gf[FN], uf[FN];
    #pragma unroll
    for (int m = 0; m < FM; ++m)
      af[m] = *reinterpret_cast<const bf16x8*>(&As[buf][(wm + m * 16 + lr15) * BK + lks]);
    #pragma unroll
    for (int n = 0; n < FN; ++n) {
      gf[n] = *reinterpret_cast<const bf16x8*>(&Gs[buf][(wn + n * 16 + lr15) * BK + lks]);
      uf[n] = *reinterpret_cast<const bf16x8*>(&Us[buf][(wn + n * 16 + lr15) * BK + lks]);
    }
    #pragma unroll
    for (int m = 0; m < FM; ++m)
      #pragma unroll
      for (int n = 0; n < FN; ++n) {
        accg[m][n] = __builtin_amdgcn_mfma_f32_16x16x32_bf16(af[m], gf[n], accg[m][n], 0, 0, 0);
        accu[m][n] = __builtin_amdgcn_mfma_f32_16x16x32_bf16(af[m], uf[n], accu[m][n], 0, 0, 0);
      }
  };

  const int NS = K / BK;
  loadB(0);
  stageA(0, 0);
  writeB(0);
  __syncthreads();
  int cur = 0;
  for (int t = 0; t < NS; ++t) {
    if (t + 1 < NS) { loadB((t + 1) * BK); stageA(cur ^ 1, (t + 1) * BK); }
    compute(cur);
    if (t + 1 < NS) {
      writeB(cur ^ 1);
      __syncthreads();
      cur ^= 1;
    }
  }

  const int r0 = (lane >> 4) << 2;
  #pragma unroll
  for (int m = 0; m < FM; ++m)
    #pragma unroll
    for (int n = 0; n < FN; ++n) {
      const int col = bn + wn + n * 16 + lr15;
      const long rowb = bm + wm + m * 16 + r0;
      #pragma unroll
      for (int j = 0; j < 4; ++j) {
        float g = accg[m][n][j], u = accu[m][n][j];
        Cb[(rowb + j) * N + col] = __float2bfloat16((g / (1.0f + expf(-g))) * u);
      }
    }
}

// ---------------- head GEMM: wave-per-output dot (tiny M=32) ----------------
template <bool GELU>
__global__ __launch_bounds__(256) void k_hgemm(const float* __restrict__ A,
                                               const float* __restrict__ W,
                                               const float* __restrict__ bias,
                                               float* __restrict__ C,
                                               int M, int N, int K) {
  int idx = blockIdx.x * 4 + (threadIdx.x >> 6);
  if (idx >= M * N) return;
  int b = idx / N, n = idx % N;
  int lane = threadIdx.x & 63;
  const float* a = A + (long)b * K;
  const float* w = W + (long)n * K;
  float s = 0.f;
  for (int k = lane * 4; k < K; k += 256) {
    float4 av = *reinterpret_cast<const float4*>(a + k);
    float4 wv = *reinterpret_cast<const float4*>(w + k);
    s = fmaf(av.x, wv.x, s); s = fmaf(av.y, wv.y, s);
    s = fmaf(av.z, wv.z, s); s = fmaf(av.w, wv.w, s);
  }
  #pragma unroll
  for (int off = 32; off; off >>= 1) s += __shfl_xor(s, off);
  if (lane == 0) {
    float v = s + bias[n];
    if (GELU) v = 0.5f * v * (1.0f + erff(v * 0.70710678118654752f));
    C[idx] = v;
  }
}

// ---- lora down (grid [T, G]): out[t*outStride + g*16 + r] = x[t] . A_g[r] --
__global__ __launch_bounds__(256) void k_lora_down3(
    const float* __restrict__ x,
    const float* __restrict__ A0, const float* __restrict__ A1, const float* __restrict__ A2,
    float* __restrict__ out, int outStride) {
  int t = blockIdx.x, g = blockIdx.y, tid = threadIdx.x;
  const float* A = (g == 0) ? A0 : (g == 1) ? A1 : A2;
  int r = tid & 15, sl = tid >> 4;
  const float* xr = x + (long)t * H + sl * 128;
  const float* Ar = A + (long)r * H + sl * 128;
  float p = 0.f;
  #pragma unroll 8
  for (int kk = 0; kk < 128; kk += 4) {
    float4 xv = *reinterpret_cast<const float4*>(xr + kk);
    float4 av = *reinterpret_cast<const float4*>(Ar + kk);
    p = fmaf(xv.x, av.x, p); p = fmaf(xv.y, av.y, p);
    p = fmaf(xv.z, av.z, p); p = fmaf(xv.w, av.w, p);
  }
  __shared__ float red[16][17];
  red[sl][r] = p;
  __syncthreads();
  if (tid < 16) {
    float s = 0.f;
    #pragma unroll
    for (int i = 0; i < 16; ++i) s += red[i][tid];
    out[(long)t * outStride + g * 16 + tid] = s;
  }
}

// ---------------- RoPE table ----------------
__global__ __launch_bounds__(256) void k_rope_tab(float2* __restrict__ tab) {
  int idx = blockIdx.x * 256 + threadIdx.x;   // 4096 entries
  if (idx >= SS * 64) return;
  int pos = idx >> 6, j = idx & 63;
  float inv = 1.0f / powf(1.0e6f, (float)(2 * j) * (1.0f / HD));
  float ang = (float)pos * inv;
  tab[idx] = make_float2(cosf(ang), sinf(ang));
}

// ============ fused attention v2: rope-on-load + LDS K/V (r12) ==============
__global__ __launch_bounds__(256) void k_attn2(const float* __restrict__ qkv,
                                               const int* __restrict__ mask,
                                               const float2* __restrict__ tab,
                                               float* __restrict__ o,
                                               __hip_bfloat16* __restrict__ obf) {
  __shared__ float Kt[128][65];
  __shared__ float Vs[64][128];
  __shared__ int   mb[64];
  const int b = blockIdx.x, kv = blockIdx.y, qz = blockIdx.z;
  const int tid = threadIdx.x, lane = tid & 63, wid = tid >> 6;
  const float* kbase = qkv + ((long)b * SS) * QKVD + H + kv * HD;
  for (int i = tid; i < 64 * 64; i += 256) {
    int j = i & 63, ki = i >> 6;
    const float* kr = kbase + (long)ki * QKVD;
    float lo = kr[j], hi = kr[j + 64];
    float2 cs = tab[ki * 64 + j];
    Kt[j][ki]      = lo * cs.x - hi * cs.y;
    Kt[j + 64][ki] = hi * cs.x + lo * cs.y;
  }
  const float* vbase = qkv + ((long)b * SS) * QKVD + H + KVD + kv * HD;
  for (int i = tid; i < 64 * 32; i += 256) {
    int f4 = i & 31, ki = i >> 5;
    *reinterpret_cast<float4*>(&Vs[ki][f4 * 4]) =
        *reinterpret_cast<const float4*>(vbase + (long)ki * QKVD + f4 * 4);
  }
  if (tid < 64) mb[tid] = mask[b * SS + tid];
  __syncthreads();

  for (int rr = 0; rr < 32; ++rr) {
    int br = wid * 32 + rr;
    int qh = br >> 4, qi = qz * 16 + (br & 15);
    int hh = kv * 8 + qh;
    long t = (long)b * SS + qi;
    const float* qr = qkv + t * QKVD + hh * HD;
    float dot = 0.f;
    #pragma unroll 8
    for (int j = 0; j < 64; ++j) {
      float2 cs = tab[qi * 64 + j];
      float lo = qr[j], hi = qr[j + 64];
      float rlo = lo * cs.x - hi * cs.y;
      float rhi = hi * cs.x + lo * cs.y;
      dot = fmaf(rlo, Kt[j][lane], dot);
      dot = fmaf(rhi, Kt[j + 64][lane], dot);
    }
    bool keep = (lane <= qi) && (mb[lane] > 0);
    float sc = dot * 0.08838834764831845f + (keep ? 0.f : -1e9f);
    float m = sc;
    #pragma unroll
    for (int off = 32; off; off >>= 1) m = fmaxf(m, __shfl_xor(m, off));
    float e = expf(sc - m);
    float s = e;
    #pragma unroll
    for (int off = 32; off; off >>= 1) s += __shfl_xor(s, off);
    float p = e / s;
    float o0 = 0.f, o1 = 0.f;
    #pragma unroll 8
    for (int ki = 0; ki < 64; ++ki) {
      float pk = __shfl(p, ki);
      o0 = fmaf(pk, Vs[ki][lane], o0);
      o1 = fmaf(pk, Vs[ki][lane + 64], o1);
    }
    long oidx = t * H + hh * HD + lane;
    o[oidx] = o0; o[oidx + 64] = o1;
    obf[oidx] = __float2bfloat16(o0);
    obf[oidx + 64] = __float2bfloat16(o1);
  }
}

// ---------------- pool last valid token ----------------
__global__ __launch_bounds__(256) void k_pool(const float* __restrict__ x,
                                              const int* __restrict__ mask,
                                              float* __restrict__ pooled) {
  int b = blockIdx.x;
  __shared__ int len;
  if (threadIdx.x == 0) {
    int L2 = 0;
    for (int i = 0; i < SS; ++i) L2 += (mask[b * SS + i] > 0);
    len = L2;
  }
  __syncthreads();
  const float4* sp = reinterpret_cast<const float4*>(x + ((long)b * SS + len - 1) * H);
  float4* dp = reinterpret_cast<float4*>(pooled + (long)b * H);
  for (int i = threadIdx.x; i < H / 4; i += 256) dp[i] = sp[i];
}

static inline int cvt_grid(long n) { return (int)((n / 4 + 255) / 256); }

extern "C" void kernel_launch(void* const* d_in, const int* in_sizes, int n_in,
                              void* d_out, int out_size, void* d_ws, size_t ws_size,
                              hipStream_t stream) {
  const int*   ids    = (const int*)d_in[0];
  const int*   mask   = (const int*)d_in[1];
  const float* embed  = (const float*)d_in[2];
  const float* Wq     = (const float*)d_in[3];
  const float* bq     = (const float*)d_in[4];
  const float* Aq     = (const float*)d_in[5];
  const float* Bq     = (const float*)d_in[6];
  const float* Wk     = (const float*)d_in[7];
  const float* bk     = (const float*)d_in[8];
  const float* Ak     = (const float*)d_in[9];
  const float* Bk     = (const float*)d_in[10];
  const float* Wv     = (const float*)d_in[11];
  const float* bv     = (const float*)d_in[12];
  const float* Av     = (const float*)d_in[13];
  const float* Bv     = (const float*)d_in[14];
  const float* Wo     = (const float*)d_in[15];
  const float* Ao     = (const float*)d_in[16];
  const float* Bo     = (const float*)d_in[17];
  const float* ln1    = (const float*)d_in[18];
  const float* ln2    = (const float*)d_in[19];
  const float* Wg     = (const float*)d_in[20];
  const float* Wu     = (const float*)d_in[21];
  const float* Wd     = (const float*)d_in[22];
  const float* norm_f = (const float*)d_in[23];
  const float* W1     = (const float*)d_in[24];
  const float* b1     = (const float*)d_in[25];
  const float* W2     = (const float*)d_in[26];
  const float* b2     = (const float*)d_in[27];

  // ---- workspace layout ----
  float* ws = (float*)d_ws;
  float* h        = ws;                           // [T,H] fp32 residual
  float* x        = h    + (long)TT * H;          // [T,H] fp32
  float* qkv      = x    + (long)TT * H;          // [T,QKVD] fp32
  float* tmpR     = qkv  + (long)TT * QKVD;       // [T,48]
  float* tmpO     = tmpR + (long)TT * 48;         // [T,16]
  float* pooled   = tmpO + (long)TT * 16;         // [B,H]
  float* zz       = pooled + (long)BB * H;        // [B,PH]
  float* biascat  = zz   + (long)BB * PH;         // [2,QKVD]
  float* bcat     = biascat + (long)NL * QKVD;    // [2,QKVD,16]
  float2* ropetab = (float2*)(bcat + (long)NL * QKVD * RR);  // [SS*64]
  float* endf32   = (float*)(ropetab + SS * 64);
  __hip_bfloat16* x_bf  = (__hip_bfloat16*)endf32;            // [T,H]
  __hip_bfloat16* ffbf  = x_bf + (long)TT * H;                // [T,FF]
  __hip_bfloat16* wgbf  = ffbf + (long)TT * FF;               // [FF,H]  Wg
  __hip_bfloat16* wubf  = wgbf + (long)FF * H;                // [FF,H]  Wu
  __hip_bfloat16* wdbf  = wubf + (long)FF * H;                // [H,FF]  Wd
  __hip_bfloat16* wqbf  = wdbf + (long)FF * H;                // [QKVD,H] qkv cat
  __hip_bfloat16* wobf  = wqbf + (long)QKVD * H;              // [H,H]   Wo
  size_t need_bf = (size_t)((char*)(wobf + (long)H * H) - (char*)d_ws);
  bool bfw = ws_size >= need_bf;

  k_embed<<<TT, 256, 0, stream>>>(ids, embed, h);
  k_rope_tab<<<(SS * 64 + 255) / 256, 256, 0, stream>>>(ropetab);
  k_prep<<<(NL * QKVD + 255) / 256, 256, 0, stream>>>(bq, bk, bv, Bq, Bk, Bv, biascat, bcat);

  for (int l = 0; l < NL; ++l) {
    const long lHH = (long)l * H * H;
    const long lKH = (long)l * KVD * H;
    const long lRH = (long)l * RR * H;
    const long lFH = (long)l * FF * H;
    // x,x_bf = rms(h, ln1)
    k_rmsnorm<<<TT, 256, 0, stream>>>(h, ln1 + l * H, x, x_bf);
    // lora downs for q/k/v in one dispatch
    k_lora_down3<<<dim3(TT, 3), 256, 0, stream>>>(
        x, Aq + lRH, Ak + lRH, Av + lRH, tmpR, 48);
    if (bfw) {
      k_cvt_qkv<<<cvt_grid((long)QKVD * H), 256, 0, stream>>>(
          Wq + lHH, Wk + lKH, Wv + lKH, wqbf);
      k_mgemm<ME_BIAS_F32, true, true><<<(TT / 64) * (QKVD / 128), 512, 0, stream>>>(
          x_bf, nullptr, nullptr, nullptr, wqbf, biascat + (long)l * QKVD, qkv,
          tmpR, bcat + (long)l * QKVD * RR, 48, 1, TT, QKVD, H);
    } else {
      k_mgemm<ME_BIAS_F32, true, false><<<(TT / 64) * (QKVD / 128), 512, 0, stream>>>(
          x_bf, Wq + lHH, Wk + lKH, Wv + lKH, nullptr, biascat + (long)l * QKVD, qkv,
          tmpR, bcat + (long)l * QKVD * RR, 48, 1, TT, QKVD, H);
    }
    // fused rope+attention (reads un-roped qkv, writes fp32 x and bf16 x_bf)
    k_attn2<<<dim3(BB, NKV, 4), 256, 0, stream>>>(qkv, mask, ropetab, x, x_bf);
    // h += attn @ Wo^T + lora
    k_lora_down3<<<dim3(TT, 1), 256, 0, stream>>>(
        x, Ao + lRH, Ao + lRH, Ao + lRH, tmpO, 16);
    if (bfw) {
      k_cvt<<<cvt_grid((long)H * H), 256, 0, stream>>>(Wo + lHH, wobf, (long)H * H);
      k_mgemm<ME_ACC_F32, true, true><<<(TT / 64) * (H / 128), 512, 0, stream>>>(
          x_bf, nullptr, nullptr, nullptr, wobf, nullptr, h,
          tmpO, Bo + (long)l * H * RR, 16, 0, TT, H, H);
    } else {
      k_mgemm<ME_ACC_F32, true, false><<<(TT / 64) * (H / 128), 512, 0, stream>>>(
          x_bf, Wo + lHH, Wo + lHH, Wo + lHH, nullptr, nullptr, h,
          tmpO, Bo + (long)l * H * RR, 16, 0, TT, H, H);
    }
    // MLP
    k_rmsnorm<<<TT, 256, 0, stream>>>(h, ln2 + l * H, x, x_bf);
    if (bfw) {
      k_cvt3<<<cvt_grid(3L * FF * H), 256, 0, stream>>>(
          Wg + lFH, Wu + lFH, Wd + lFH, wgbf);   // wgbf|wubf|wdbf contiguous
      k_swiglu_b<<<(TT / 128) * (FF / 128), 512, 0, stream>>>(
          x_bf, wgbf, wubf, ffbf, TT, FF, H);
      k_mgemm<ME_ACC_F32, false, true><<<(TT / 64) * (H / 128), 512, 0, stream>>>(
          ffbf, nullptr, nullptr, nullptr, wdbf, nullptr, h,
          nullptr, nullptr, 0, 0, TT, H, FF);
    } else {
      k_swiglu<<<(TT / 128) * (FF / 128), 256, 0, stream>>>(
          x_bf, Wg + lFH, Wu + lFH, ffbf, TT, FF, H);
      k_mgemm<ME_ACC_F32, false, false><<<(TT / 64) * (H / 128), 512, 0, stream>>>(
          ffbf, Wd + lFH, Wd + lFH, Wd + lFH, nullptr, nullptr, h,
          nullptr, nullptr, 0, 0, TT, H, FF);
    }
  }

  // final norm, pool, head (wave-per-output dot GEMMs)
  k_rmsnorm<<<TT, 256, 0, stream>>>(h, norm_f, x, x_bf);
  k_pool<<<BB, 256, 0, stream>>>(x, mask, pooled);
  k_hgemm<true><<<(BB * PH + 3) / 4, 256, 0, stream>>>(pooled, W1, b1, zz, BB, PH, H);
  k_hgemm<false><<<(BB * TDm + 3) / 4, 256, 0, stream>>>(zz, W2, b2, (float*)d_out, BB, TDm, PH);
}

// Round 17
// 1798.857 us; speedup vs baseline: 1.0114x; 1.0114x over previous
//
#include <hip/hip_runtime.h>
#include <hip/hip_bf16.h>
#include <math.h>

namespace {
constexpr int NL  = 2;          // layers
constexpr int H   = 2048;
constexpr int NH  = 16;
constexpr int NKV = 2;
constexpr int HD  = 128;
constexpr int FF  = 11008;
constexpr int BB  = 32;         // batch
constexpr int SS  = 64;         // seq
constexpr int RR  = 16;         // lora rank
constexpr int TT  = BB * SS;    // 2048 tokens
constexpr int KVD = NKV * HD;   // 256
constexpr int QKVD = H + 2 * KVD; // 2560 fused qkv width
constexpr int PH  = 1024, TDm = 512;
constexpr float LSCALE = 2.0f;  // lora alpha/r
}

typedef __bf16 bf16x8 __attribute__((ext_vector_type(8)));
typedef float  f32x4  __attribute__((ext_vector_type(4)));

__device__ __forceinline__ ushort4 f4_to_bf4(float4 r) {
  __hip_bfloat16 a = __float2bfloat16(r.x), b = __float2bfloat16(r.y),
                 c = __float2bfloat16(r.z), d = __float2bfloat16(r.w);
  return make_ushort4(*(unsigned short*)&a, *(unsigned short*)&b,
                      *(unsigned short*)&c, *(unsigned short*)&d);
}

__device__ __forceinline__ bf16x8 f8cvt(float4 a, float4 b) {
  bf16x8 r;
  r[0] = (__bf16)a.x; r[1] = (__bf16)a.y; r[2] = (__bf16)a.z; r[3] = (__bf16)a.w;
  r[4] = (__bf16)b.x; r[5] = (__bf16)b.y; r[6] = (__bf16)b.z; r[7] = (__bf16)b.w;
  return r;
}

__device__ __forceinline__ float dot4(float4 a, float4 b) {
  return a.x * b.x + a.y * b.y + a.z * b.z + a.w * b.w;
}

// ---------------- embedding gather ----------------
__global__ __launch_bounds__(256) void k_embed(const int* __restrict__ ids,
                                               const float* __restrict__ emb,
                                               float* __restrict__ h) {
  int t = blockIdx.x;
  long id = ids[t];
  const float4* src = reinterpret_cast<const float4*>(emb + id * (long)H);
  float4* dst = reinterpret_cast<float4*>(h + (long)t * H);
  for (int i = threadIdx.x; i < H / 4; i += 256) dst[i] = src[i];
}

// ---------------- fp32 -> bf16 converts ----------------
__global__ __launch_bounds__(256) void k_cvt(const float* __restrict__ src,
                                             __hip_bfloat16* __restrict__ dst, long n) {
  long i = ((long)blockIdx.x * 256 + threadIdx.x) * 4;
  if (i >= n) return;
  float4 v = *reinterpret_cast<const float4*>(src + i);
  *reinterpret_cast<ushort4*>(dst + i) = f4_to_bf4(v);
}

// QKV concat convert (3 sources -> one dst) — one dispatch per layer
__global__ __launch_bounds__(256) void k_cvt_qkv(
    const float* __restrict__ Wq, const float* __restrict__ Wk,
    const float* __restrict__ Wv, __hip_bfloat16* __restrict__ dst) {
  long i = ((long)blockIdx.x * 256 + threadIdx.x) * 4;
  const long n1 = (long)H * H, n2 = n1 + (long)KVD * H, nt = (long)QKVD * H;
  if (i >= nt) return;
  const float* src; long off;
  if (i < n1)      { src = Wq; off = i; }
  else if (i < n2) { src = Wk; off = i - n1; }
  else             { src = Wv; off = i - n2; }
  float4 v = *reinterpret_cast<const float4*>(src + off);
  *reinterpret_cast<ushort4*>(dst + i) = f4_to_bf4(v);
}

// Wg/Wu/Wd convert (3 equal regions, contiguous dsts) — one dispatch
__global__ __launch_bounds__(256) void k_cvt3(
    const float* __restrict__ s0, const float* __restrict__ s1,
    const float* __restrict__ s2, __hip_bfloat16* __restrict__ dst) {
  long i = ((long)blockIdx.x * 256 + threadIdx.x) * 4;
  const long n = (long)FF * H;
  if (i >= 3 * n) return;
  const float* src; long off;
  if (i < n)          { src = s0; off = i; }
  else if (i < 2 * n) { src = s1; off = i - n; }
  else                { src = s2; off = i - 2 * n; }
  float4 v = *reinterpret_cast<const float4*>(src + off);
  *reinterpret_cast<ushort4*>(dst + i) = f4_to_bf4(v);
}

// ---------------- prep: biascat + Bcat for both layers ----------------
__global__ __launch_bounds__(256) void k_prep(
    const float* __restrict__ bq, const float* __restrict__ bk, const float* __restrict__ bv,
    const float* __restrict__ Bq, const float* __restrict__ Bk, const float* __restrict__ Bv,
    float* __restrict__ biascat, float* __restrict__ bcat) {
  int idx = blockIdx.x * 256 + threadIdx.x;   // l*QKVD + col
  if (idx >= NL * QKVD) return;
  int l = idx / QKVD, col = idx % QKVD;
  const float* bsrc; const float* Bsrc;
  if (col < H)            { bsrc = bq + (long)l * H + col;            Bsrc = Bq + ((long)l * H + col) * RR; }
  else if (col < H + KVD) { bsrc = bk + (long)l * KVD + (col - H);    Bsrc = Bk + ((long)l * KVD + col - H) * RR; }
  else                    { bsrc = bv + (long)l * KVD + (col - H - KVD); Bsrc = Bv + ((long)l * KVD + col - H - KVD) * RR; }
  biascat[idx] = *bsrc;
  #pragma unroll
  for (int r = 0; r < RR; ++r) bcat[(long)idx * RR + r] = Bsrc[r];
}

// ---------------- rmsnorm (block per token), dual fp32+bf16 out -----------
__global__ __launch_bounds__(256) void k_rmsnorm(const float* __restrict__ in,
                                                 const float* __restrict__ w,
                                                 float* __restrict__ out,
                                                 __hip_bfloat16* __restrict__ outb) {
  int t = blockIdx.x, tid = threadIdx.x;
  const float4* xr = reinterpret_cast<const float4*>(in + (long)t * H);
  float4 v0 = xr[tid], v1 = xr[tid + 256];
  float ss = v0.x*v0.x + v0.y*v0.y + v0.z*v0.z + v0.w*v0.w
           + v1.x*v1.x + v1.y*v1.y + v1.z*v1.z + v1.w*v1.w;
  #pragma unroll
  for (int off = 32; off; off >>= 1) ss += __shfl_xor(ss, off);
  __shared__ float sred[4];
  if ((tid & 63) == 0) sred[tid >> 6] = ss;
  __syncthreads();
  float scale = rsqrtf((sred[0] + sred[1] + sred[2] + sred[3]) * (1.0f / H) + 1e-6f);
  const float4* wr = reinterpret_cast<const float4*>(w);
  float4 w0 = wr[tid], w1 = wr[tid + 256];
  float4 r0 = make_float4(v0.x*scale*w0.x, v0.y*scale*w0.y, v0.z*scale*w0.z, v0.w*scale*w0.w);
  float4 r1 = make_float4(v1.x*scale*w1.x, v1.y*scale*w1.y, v1.z*scale*w1.z, v1.w*scale*w1.w);
  float4* o = reinterpret_cast<float4*>(out + (long)t * H);
  o[tid] = r0; o[tid + 256] = r1;
  ushort4* ob = reinterpret_cast<ushort4*>(outb + (long)t * H);
  ob[tid] = f4_to_bf4(r0); ob[tid + 256] = f4_to_bf4(r1);
}

// ===================== MFMA bf16 GEMM, fused LoRA (r11/r15 final) ==========
// 256 thr / 4 waves, per-wave 64x32 (FM=4, FN=2). BM=64 BN=128 BK=64,
// 48KB LDS -> 2 blocks/CU. (r16: 8-wave/FN=1 split was null — per-wave MFMA
// work halves with the split, so compute:drain ratio is unchanged. KEEP 4-wave.)
enum { ME_BIAS_F32 = 0, ME_ACC_F32 = 1 };

__device__ __forceinline__ int raster_sw(int bid, int nwg) {
  // bijective XCD remap (m204)
  int q8 = nwg >> 3, r8 = nwg & 7;
  int xcd = bid & 7, pos = bid >> 3;
  return (xcd < r8 ? xcd * (q8 + 1) : r8 * (q8 + 1) + (xcd - r8) * q8) + pos;
}

template <int EPI, bool LORA, bool WBF16>
__global__ __launch_bounds__(256, 3) void k_mgemm(
    const __hip_bfloat16* __restrict__ Abf,
    const float* __restrict__ W0, const float* __restrict__ W1, const float* __restrict__ W2,
    const __hip_bfloat16* __restrict__ Wb,
    const float* __restrict__ bias,
    float* __restrict__ Cf,
    const float* __restrict__ lt, const float* __restrict__ lB, int ltStride,
    int qkvMode, int M, int N, int K) {
  constexpr int BM = 64, BN = 128, BK = 64;
  constexpr int FM = 4, FN = 2;            // per-wave 64x32
  __shared__ __align__(16) __bf16 As[2][BM * BK];   // 8 KB x2
  __shared__ __align__(16) __bf16 Bs[2][BN * BK];   // 16 KB x2
  const int tid = threadIdx.x;
  const int sw = raster_sw(blockIdx.x, gridDim.x);
  const int ntm = M / BM;
  const int bm = (sw % ntm) * BM, bn = (sw / ntm) * BN;   // col-major raster
  const int lane = tid & 63, wv = tid >> 6;               // 4 waves
  const int wn = wv * 32;
  const int lr15 = lane & 15;
  const int g4 = lane >> 4;                               // k-chunk group 0..3
  f32x4 acc[FM][FN] = {};
  const __bf16* Ag = reinterpret_cast<const __bf16*>(Abf) + (long)bm * K;

  const float* Wsrc = W0; int wrow0 = bn;
  if constexpr (!WBF16) {
    if (qkvMode) {
      if (bn >= H + KVD)      { Wsrc = W2; wrow0 = bn - (H + KVD); }
      else if (bn >= H)       { Wsrc = W1; wrow0 = bn - H; }
    }
  }
  const __bf16* Wg16 = reinterpret_cast<const __bf16*>(Wb) + (long)bn * K;

  const int arow = tid >> 3, acol = tid & 7;

  auto stageA = [&](int buf, int k0) {
    __builtin_amdgcn_global_load_lds(
        (const __attribute__((address_space(1))) void*)
          (Ag + (long)arow * K + k0 + ((acol ^ (arow & 7)) << 3)),
        (__attribute__((address_space(3))) void*)(&As[buf][tid * 8]), 16, 0, 0);
    int r1 = arow + 32;
    __builtin_amdgcn_global_load_lds(
        (const __attribute__((address_space(1))) void*)
          (Ag + (long)r1 * K + k0 + ((acol ^ (r1 & 7)) << 3)),
        (__attribute__((address_space(3))) void*)(&As[buf][(tid + 256) * 8]), 16, 0, 0);
  };

  auto stageB16 = [&](int buf, int k0) {
    #pragma unroll
    for (int q = 0; q < 4; ++q) {
      int c = tid + q * 256;
      int row = c >> 3, col = c & 7;
      __builtin_amdgcn_global_load_lds(
          (const __attribute__((address_space(1))) void*)
            (Wg16 + (long)row * K + k0 + ((col ^ (row & 7)) << 3)),
          (__attribute__((address_space(3))) void*)(&Bs[buf][c * 8]), 16, 0, 0);
    }
  };

  float4 bb[4][2];
  auto loadB = [&](int k0) {
    #pragma unroll
    for (int q = 0; q < 4; ++q) {
      int r = arow + q * 32;
      const float* p = Wsrc + (long)(wrow0 + r) * K + k0 + ((acol ^ (r & 7)) << 3);
      bb[q][0] = *reinterpret_cast<const float4*>(p);
      bb[q][1] = *reinterpret_cast<const float4*>(p + 4);
    }
  };
  auto writeB = [&](int buf) {
    #pragma unroll
    for (int q = 0; q < 4; ++q)
      *reinterpret_cast<bf16x8*>(&Bs[buf][(tid + q * 256) * 8]) = f8cvt(bb[q][0], bb[q][1]);
  };

  auto compute = [&](int buf) {
    #pragma unroll
    for (int ks = 0; ks < 2; ++ks) {
      bf16x8 af[FM], bfr[FN];
      #pragma unroll
      for (int m = 0; m < FM; ++m) {
        int row = m * 16 + lr15;
        af[m] = *reinterpret_cast<const bf16x8*>(
            &As[buf][row * BK + (((g4 + 4 * ks) ^ (row & 7)) << 3)]);
      }
      #pragma unroll
      for (int n = 0; n < FN; ++n) {
        int row = wn + n * 16 + lr15;
        bfr[n] = *reinterpret_cast<const bf16x8*>(
            &Bs[buf][row * BK + (((g4 + 4 * ks) ^ (row & 7)) << 3)]);
      }
      #pragma unroll
      for (int m = 0; m < FM; ++m)
        #pragma unroll
        for (int n = 0; n < FN; ++n)
          acc[m][n] = __builtin_amdgcn_mfma_f32_16x16x32_bf16(af[m], bfr[n], acc[m][n], 0, 0, 0);
    }
  };

  const int NS = K / BK;
  if constexpr (WBF16) {
    stageA(0, 0); stageB16(0, 0);
    __syncthreads();
    int cur = 0;
    for (int t = 0; t < NS; ++t) {
      if (t + 1 < NS) { stageA(cur ^ 1, (t + 1) * BK); stageB16(cur ^ 1, (t + 1) * BK); }
      compute(cur);
      if (t + 1 < NS) { __syncthreads(); cur ^= 1; }
    }
  } else {
    loadB(0);
    stageA(0, 0);
    writeB(0);
    __syncthreads();
    int cur = 0;
    for (int t = 0; t < NS; ++t) {
      if (t + 1 < NS) { loadB((t + 1) * BK); stageA(cur ^ 1, (t + 1) * BK); }
      compute(cur);
      if (t + 1 < NS) {
        writeB(cur ^ 1);
        __syncthreads();
        cur ^= 1;
      }
    }
  }

  // ---- epilogue: bias / accumulate, optional fused LoRA ----
  const int r0 = g4 << 2;
  float4 lb[FN][4];
  int goff = 0;
  if constexpr (LORA) {
    if (qkvMode) goff = (bn >= H + KVD) ? 32 : (bn >= H ? 16 : 0);
    #pragma unroll
    for (int n = 0; n < FN; ++n) {
      const float4* p = reinterpret_cast<const float4*>(lB + (long)(bn + wn + n * 16 + lr15) * RR);
      lb[n][0] = p[0]; lb[n][1] = p[1]; lb[n][2] = p[2]; lb[n][3] = p[3];
    }
  }
  float bcol[FN];
  if constexpr (EPI == ME_BIAS_F32) {
    #pragma unroll
    for (int n = 0; n < FN; ++n) bcol[n] = bias[bn + wn + n * 16 + lr15];
  }
  #pragma unroll
  for (int m = 0; m < FM; ++m)
    #pragma unroll
    for (int j = 0; j < 4; ++j) {
      const long row = bm + m * 16 + r0 + j;
      float lv[FN];
      if constexpr (LORA) {
        const float4* tp = reinterpret_cast<const float4*>(lt + row * ltStride + goff);
        float4 t0 = tp[0], t1 = tp[1], t2 = tp[2], t3 = tp[3];
        #pragma unroll
        for (int n = 0; n < FN; ++n)
          lv[n] = LSCALE * (dot4(t0, lb[n][0]) + dot4(t1, lb[n][1]) +
                            dot4(t2, lb[n][2]) + dot4(t3, lb[n][3]));
      }
      #pragma unroll
      for (int n = 0; n < FN; ++n) {
        const int col = bn + wn + n * 16 + lr15;
        float v = acc[m][n][j];
        if constexpr (LORA) v += lv[n];
        if constexpr (EPI == ME_BIAS_F32) Cf[row * N + col] = v + bcol[n];
        else                              Cf[row * N + col] += v;
      }
    }
}

// ------ fused SwiGLU, bf16 weights, 512 thr / 8 waves (r15: 238us) ---------
// 128x128 tile + BK=32 + 48KB LDS; 8 waves (2x4) each 64x32 (FM=4,FN=2).
// Occupancy 38.6%, MfmaUtil 33.7% — session-best config, keep exactly.
__global__ __launch_bounds__(512, 1) void k_swiglu_b(
    const __hip_bfloat16* __restrict__ Abf,
    const __hip_bfloat16* __restrict__ Wgb,
    const __hip_bfloat16* __restrict__ Wub,
    __hip_bfloat16* __restrict__ Cb,
    int M, int N, int K) {
  constexpr int BM = 128, BN = 128, BK = 32;
  constexpr int FM = 4, FN = 2;
  __shared__ __align__(16) __bf16 As[2][BM * BK];
  __shared__ __align__(16) __bf16 Gs[2][BN * BK];
  __shared__ __align__(16) __bf16 Us[2][BN * BK];
  const int tid = threadIdx.x;
  const int sw = raster_sw(blockIdx.x, gridDim.x);
  const int ntm = M / BM;
  const int bm = (sw % ntm) * BM, bn = (sw / ntm) * BN;
  const int lane = tid & 63, wid = tid >> 6;            // 8 waves (2x4)
  const int wm = (wid >> 2) * 64, wn = (wid & 3) * 32;
  const int lr15 = lane & 15;
  const int lks = (((lane >> 4) << 3)) ^ ((((lr15 >> 1) & 3)) << 3);
  f32x4 accg[FM][FN] = {}, accu[FM][FN] = {};
  const __bf16* Ag = reinterpret_cast<const __bf16*>(Abf) + (long)bm * K;
  const __bf16* Gg = reinterpret_cast<const __bf16*>(Wgb) + (long)bn * K;
  const __bf16* Ug = reinterpret_cast<const __bf16*>(Wub) + (long)bn * K;

  auto stage = [&](int buf, int k0) {
    const int i = tid;   // 512 threads cover 512 chunks/operand
    const int sc = ((i & 3) ^ ((i >> 3) & 3)) << 3;
    const long ro = (long)(i >> 2) * K + k0 + sc;
    __builtin_amdgcn_global_load_lds(
        (const __attribute__((address_space(1))) void*)(Ag + ro),
        (__attribute__((address_space(3))) void*)(&As[buf][i * 8]), 16, 0, 0);
    __builtin_amdgcn_global_load_lds(
        (const __attribute__((address_space(1))) void*)(Gg + ro),
        (__attribute__((address_space(3))) void*)(&Gs[buf][i * 8]), 16, 0, 0);
    __builtin_amdgcn_global_load_lds(
        (const __attribute__((address_space(1))) void*)(Ug + ro),
        (__attribute__((address_space(3))) void*)(&Us[buf][i * 8]), 16, 0, 0);
  };
  auto compute = [&](int buf) {
    bf16x8 af[FM], gf[FN], uf[FN];
    #pragma unroll
    for (int m = 0; m < FM; ++m)
      af[m] = *reinterpret_cast<const bf16x8*>(&As[buf][(wm + m * 16 + lr15) * BK + lks]);
    #pragma unroll
    for (int n = 0; n < FN; ++n) {
      gf[n] = *reinterpret_cast<const bf16x8*>(&Gs[buf][(wn + n * 16 + lr15) * BK + lks]);
      uf[n] = *reinterpret_cast<const bf16x8*>(&Us[buf][(wn + n * 16 + lr15) * BK + lks]);
    }
    #pragma unroll
    for (int m = 0; m < FM; ++m)
      #pragma unroll
      for (int n = 0; n < FN; ++n) {
        accg[m][n] = __builtin_amdgcn_mfma_f32_16x16x32_bf16(af[m], gf[n], accg[m][n], 0, 0, 0);
        accu[m][n] = __builtin_amdgcn_mfma_f32_16x16x32_bf16(af[m], uf[n], accu[m][n], 0, 0, 0);
      }
  };

  const int NS = K / BK;
  stage(0, 0);
  asm volatile("s_waitcnt vmcnt(0)" ::: "memory");
  __builtin_amdgcn_s_barrier();
  int cur = 0;
  for (int t = 0; t < NS; ++t) {
    if (t + 1 < NS) stage(cur ^ 1, (t + 1) * BK);
    compute(cur);
    if (t + 1 < NS) {
      asm volatile("s_waitcnt vmcnt(0)" ::: "memory");
      __builtin_amdgcn_s_barrier();
      cur ^= 1;
    }
  }

  const int r0 = (lane >> 4) << 2;
  #pragma unroll
  for (int m = 0; m < FM; ++m)
    #pragma unroll
    for (int n = 0; n < FN; ++n) {
      const int col = bn + wn + n * 16 + lr15;
      const long rowb = bm + wm + m * 16 + r0;
      #pragma unroll
      for (int j = 0; j < 4; ++j) {
        float g = accg[m][n][j], u = accu[m][n][j];
        Cb[(rowb + j) * N + col] = __float2bfloat16((g / (1.0f + expf(-g))) * u);
      }
    }
}

// ------------- fallback fused SwiGLU (fp32-direct weights, r9) -------------
__global__ __launch_bounds__(256, 2) void k_swiglu(
    const __hip_bfloat16* __restrict__ Abf,
    const float* __restrict__ Wg,
    const float* __restrict__ Wu,
    __hip_bfloat16* __restrict__ Cb,
    int M, int N, int K) {
  constexpr int BM = 128, BN = 128, BK = 32;
  constexpr int FM = 4, FN = 4;
  __shared__ __align__(16) __bf16 As[2][BM * BK];
  __shared__ __align__(16) __bf16 Gs[2][BN * BK];
  __shared__ __align__(16) __bf16 Us[2][BN * BK];
  const int tid = threadIdx.x;
  const int sw = raster_sw(blockIdx.x, gridDim.x);
  const int ntm = M / BM;
  const int bm = (sw % ntm) * BM, bn = (sw / ntm) * BN;
  const int lane = tid & 63, wv = tid >> 6;
  const int wm = (wv >> 1) * 64, wn = (wv & 1) * 64;
  const int lr15 = lane & 15;
  const int lks = (((lane >> 4) << 3)) ^ ((((lr15 >> 1) & 3)) << 3);
  f32x4 accg[FM][FN] = {}, accu[FM][FN] = {};
  const __bf16* Ag = reinterpret_cast<const __bf16*>(Abf) + (long)bm * K;

  const int br0 = tid >> 2, bc = tid & 3;
  const int br1 = br0 + 64;
  const float* gp0 = Wg + (long)(bn + br0) * K + bc * 8;
  const float* gp1 = Wg + (long)(bn + br1) * K + bc * 8;
  const float* up0 = Wu + (long)(bn + br0) * K + bc * 8;
  const float* up1 = Wu + (long)(bn + br1) * K + bc * 8;
  const int d0 = br0 * BK + ((bc ^ ((br0 >> 1) & 3)) << 3);
  const int d1 = br1 * BK + ((bc ^ ((br1 >> 1) & 3)) << 3);

  float4 g00, g01, g10, g11, u00, u01, u10, u11;
  auto loadB = [&](int k0) {
    g00 = *reinterpret_cast<const float4*>(gp0 + k0);
    g01 = *reinterpret_cast<const float4*>(gp0 + k0 + 4);
    g10 = *reinterpret_cast<const float4*>(gp1 + k0);
    g11 = *reinterpret_cast<const float4*>(gp1 + k0 + 4);
    u00 = *reinterpret_cast<const float4*>(up0 + k0);
    u01 = *reinterpret_cast<const float4*>(up0 + k0 + 4);
    u10 = *reinterpret_cast<const float4*>(up1 + k0);
    u11 = *reinterpret_cast<const float4*>(up1 + k0 + 4);
  };
  auto writeB = [&](int buf) {
    *reinterpret_cast<bf16x8*>(&Gs[buf][d0]) = f8cvt(g00, g01);
    *reinterpret_cast<bf16x8*>(&Gs[buf][d1]) = f8cvt(g10, g11);
    *reinterpret_cast<bf16x8*>(&Us[buf][d0]) = f8cvt(u00, u01);
    *reinterpret_cast<bf16x8*>(&Us[buf][d1]) = f8cvt(u10, u11);
  };
  auto stageA = [&](int buf, int k0) {
    #pragma unroll
    for (int i = tid; i < BM * BK / 8; i += 256)
      __builtin_amdgcn_global_load_lds(
          (const __attribute__((address_space(1))) void*)
            (Ag + (long)(i >> 2) * K + k0 + (((i & 3) ^ ((i >> 3) & 3)) << 3)),
          (__attribute__((address_space(3))) void*)(&As[buf][i * 8]), 16, 0, 0);
  };
  auto compute = [&](int buf) {
    bf16x8 af[FM], gf[FN], uf[FN];
    #pragma unroll
    for (int m = 0; m < FM; ++m)
      af[m] = *reinterpret_cast<const bf16x8*>(&As[buf][(wm + m * 16 + lr15) * BK + lks]);
    #pragma unroll
    for (int n = 0; n < FN; ++n) {
      gf[n] = *reinterpret_cast<const bf16x8*>(&Gs[buf][(wn + n * 16 + lr15) * BK + lks]);
      uf[n] = *reinterpret_cast<const bf16x8*>(&Us[buf][(wn + n * 16 + lr15) * BK + lks]);
    }
    #pragma unroll
    for (int m = 0; m < FM; ++m)
      #pragma unroll
      for (int n = 0; n < FN; ++n) {
        accg[m][n] = __builtin_amdgcn_mfma_f32_16x16x32_bf16(af[m], gf[n], accg[m][n], 0, 0, 0);
        accu[m][n] = __builtin_amdgcn_mfma_f32_16x16x32_bf16(af[m], uf[n], accu[m][n], 0, 0, 0);
      }
  };

  const int NS = K / BK;
  loadB(0);
  stageA(0, 0);
  writeB(0);
  __syncthreads();
  int cur = 0;
  for (int t = 0; t < NS; ++t) {
    if (t + 1 < NS) { loadB((t + 1) * BK); stageA(cur ^ 1, (t + 1) * BK); }
    compute(cur);
    if (t + 1 < NS) {
      writeB(cur ^ 1);
      __syncthreads();
      cur ^= 1;
    }
  }

  const int r0 = (lane >> 4) << 2;
  #pragma unroll
  for (int m = 0; m < FM; ++m)
    #pragma unroll
    for (int n = 0; n < FN; ++n) {
      const int col = bn + wn + n * 16 + lr15;
      const long rowb = bm + wm + m * 16 + r0;
      #pragma unroll
      for (int j = 0; j < 4; ++j) {
        float g = accg[m][n][j], u = accu[m][n][j];
        Cb[(rowb + j) * N + col] = __float2bfloat16((g / (1.0f + expf(-g))) * u);
      }
    }
}

// ---------------- head GEMM: wave-per-output dot (tiny M=32) ----------------
template <bool GELU>
__global__ __launch_bounds__(256) void k_hgemm(const float* __restrict__ A,
                                               const float* __restrict__ W,
                                               const float* __restrict__ bias,
                                               float* __restrict__ C,
                                               int M, int N, int K) {
  int idx = blockIdx.x * 4 + (threadIdx.x >> 6);
  if (idx >= M * N) return;
  int b = idx / N, n = idx % N;
  int lane = threadIdx.x & 63;
  const float* a = A + (long)b * K;
  const float* w = W + (long)n * K;
  float s = 0.f;
  for (int k = lane * 4; k < K; k += 256) {
    float4 av = *reinterpret_cast<const float4*>(a + k);
    float4 wv = *reinterpret_cast<const float4*>(w + k);
    s = fmaf(av.x, wv.x, s); s = fmaf(av.y, wv.y, s);
    s = fmaf(av.z, wv.z, s); s = fmaf(av.w, wv.w, s);
  }
  #pragma unroll
  for (int off = 32; off; off >>= 1) s += __shfl_xor(s, off);
  if (lane == 0) {
    float v = s + bias[n];
    if (GELU) v = 0.5f * v * (1.0f + erff(v * 0.70710678118654752f));
    C[idx] = v;
  }
}

// ---- lora down (grid [T, G]): out[t*outStride + g*16 + r] = x[t] . A_g[r] --
__global__ __launch_bounds__(256) void k_lora_down3(
    const float* __restrict__ x,
    const float* __restrict__ A0, const float* __restrict__ A1, const float* __restrict__ A2,
    float* __restrict__ out, int outStride) {
  int t = blockIdx.x, g = blockIdx.y, tid = threadIdx.x;
  const float* A = (g == 0) ? A0 : (g == 1) ? A1 : A2;
  int r = tid & 15, sl = tid >> 4;
  const float* xr = x + (long)t * H + sl * 128;
  const float* Ar = A + (long)r * H + sl * 128;
  float p = 0.f;
  #pragma unroll 8
  for (int kk = 0; kk < 128; kk += 4) {
    float4 xv = *reinterpret_cast<const float4*>(xr + kk);
    float4 av = *reinterpret_cast<const float4*>(Ar + kk);
    p = fmaf(xv.x, av.x, p); p = fmaf(xv.y, av.y, p);
    p = fmaf(xv.z, av.z, p); p = fmaf(xv.w, av.w, p);
  }
  __shared__ float red[16][17];
  red[sl][r] = p;
  __syncthreads();
  if (tid < 16) {
    float s = 0.f;
    #pragma unroll
    for (int i = 0; i < 16; ++i) s += red[i][tid];
    out[(long)t * outStride + g * 16 + tid] = s;
  }
}

// ---------------- RoPE table ----------------
__global__ __launch_bounds__(256) void k_rope_tab(float2* __restrict__ tab) {
  int idx = blockIdx.x * 256 + threadIdx.x;   // 4096 entries
  if (idx >= SS * 64) return;
  int pos = idx >> 6, j = idx & 63;
  float inv = 1.0f / powf(1.0e6f, (float)(2 * j) * (1.0f / HD));
  float ang = (float)pos * inv;
  tab[idx] = make_float2(cosf(ang), sinf(ang));
}

// ============ fused attention v2: rope-on-load + LDS K/V (r12) ==============
__global__ __launch_bounds__(256) void k_attn2(const float* __restrict__ qkv,
                                               const int* __restrict__ mask,
                                               const float2* __restrict__ tab,
                                               float* __restrict__ o,
                                               __hip_bfloat16* __restrict__ obf) {
  __shared__ float Kt[128][65];
  __shared__ float Vs[64][128];
  __shared__ int   mb[64];
  const int b = blockIdx.x, kv = blockIdx.y, qz = blockIdx.z;
  const int tid = threadIdx.x, lane = tid & 63, wid = tid >> 6;
  const float* kbase = qkv + ((long)b * SS) * QKVD + H + kv * HD;
  for (int i = tid; i < 64 * 64; i += 256) {
    int j = i & 63, ki = i >> 6;
    const float* kr = kbase + (long)ki * QKVD;
    float lo = kr[j], hi = kr[j + 64];
    float2 cs = tab[ki * 64 + j];
    Kt[j][ki]      = lo * cs.x - hi * cs.y;
    Kt[j + 64][ki] = hi * cs.x + lo * cs.y;
  }
  const float* vbase = qkv + ((long)b * SS) * QKVD + H + KVD + kv * HD;
  for (int i = tid; i < 64 * 32; i += 256) {
    int f4 = i & 31, ki = i >> 5;
    *reinterpret_cast<float4*>(&Vs[ki][f4 * 4]) =
        *reinterpret_cast<const float4*>(vbase + (long)ki * QKVD + f4 * 4);
  }
  if (tid < 64) mb[tid] = mask[b * SS + tid];
  __syncthreads();

  for (int rr = 0; rr < 32; ++rr) {
    int br = wid * 32 + rr;
    int qh = br >> 4, qi = qz * 16 + (br & 15);
    int hh = kv * 8 + qh;
    long t = (long)b * SS + qi;
    const float* qr = qkv + t * QKVD + hh * HD;
    float dot = 0.f;
    #pragma unroll 8
    for (int j = 0; j < 64; ++j) {
      float2 cs = tab[qi * 64 + j];
      float lo = qr[j], hi = qr[j + 64];
      float rlo = lo * cs.x - hi * cs.y;
      float rhi = hi * cs.x + lo * cs.y;
      dot = fmaf(rlo, Kt[j][lane], dot);
      dot = fmaf(rhi, Kt[j + 64][lane], dot);
    }
    bool keep = (lane <= qi) && (mb[lane] > 0);
    float sc = dot * 0.08838834764831845f + (keep ? 0.f : -1e9f);
    float m = sc;
    #pragma unroll
    for (int off = 32; off; off >>= 1) m = fmaxf(m, __shfl_xor(m, off));
    float e = expf(sc - m);
    float s = e;
    #pragma unroll
    for (int off = 32; off; off >>= 1) s += __shfl_xor(s, off);
    float p = e / s;
    float o0 = 0.f, o1 = 0.f;
    #pragma unroll 8
    for (int ki = 0; ki < 64; ++ki) {
      float pk = __shfl(p, ki);
      o0 = fmaf(pk, Vs[ki][lane], o0);
      o1 = fmaf(pk, Vs[ki][lane + 64], o1);
    }
    long oidx = t * H + hh * HD + lane;
    o[oidx] = o0; o[oidx + 64] = o1;
    obf[oidx] = __float2bfloat16(o0);
    obf[oidx + 64] = __float2bfloat16(o1);
  }
}

// ---------------- pool last valid token ----------------
__global__ __launch_bounds__(256) void k_pool(const float* __restrict__ x,
                                              const int* __restrict__ mask,
                                              float* __restrict__ pooled) {
  int b = blockIdx.x;
  __shared__ int len;
  if (threadIdx.x == 0) {
    int L2 = 0;
    for (int i = 0; i < SS; ++i) L2 += (mask[b * SS + i] > 0);
    len = L2;
  }
  __syncthreads();
  const float4* sp = reinterpret_cast<const float4*>(x + ((long)b * SS + len - 1) * H);
  float4* dp = reinterpret_cast<float4*>(pooled + (long)b * H);
  for (int i = threadIdx.x; i < H / 4; i += 256) dp[i] = sp[i];
}

static inline int cvt_grid(long n) { return (int)((n / 4 + 255) / 256); }

extern "C" void kernel_launch(void* const* d_in, const int* in_sizes, int n_in,
                              void* d_out, int out_size, void* d_ws, size_t ws_size,
                              hipStream_t stream) {
  const int*   ids    = (const int*)d_in[0];
  const int*   mask   = (const int*)d_in[1];
  const float* embed  = (const float*)d_in[2];
  const float* Wq     = (const float*)d_in[3];
  const float* bq     = (const float*)d_in[4];
  const float* Aq     = (const float*)d_in[5];
  const float* Bq     = (const float*)d_in[6];
  const float* Wk     = (const float*)d_in[7];
  const float* bk     = (const float*)d_in[8];
  const float* Ak     = (const float*)d_in[9];
  const float* Bk     = (const float*)d_in[10];
  const float* Wv     = (const float*)d_in[11];
  const float* bv     = (const float*)d_in[12];
  const float* Av     = (const float*)d_in[13];
  const float* Bv     = (const float*)d_in[14];
  const float* Wo     = (const float*)d_in[15];
  const float* Ao     = (const float*)d_in[16];
  const float* Bo     = (const float*)d_in[17];
  const float* ln1    = (const float*)d_in[18];
  const float* ln2    = (const float*)d_in[19];
  const float* Wg     = (const float*)d_in[20];
  const float* Wu     = (const float*)d_in[21];
  const float* Wd     = (const float*)d_in[22];
  const float* norm_f = (const float*)d_in[23];
  const float* W1     = (const float*)d_in[24];
  const float* b1     = (const float*)d_in[25];
  const float* W2     = (const float*)d_in[26];
  const float* b2     = (const float*)d_in[27];

  // ---- workspace layout ----
  float* ws = (float*)d_ws;
  float* h        = ws;                           // [T,H] fp32 residual
  float* x        = h    + (long)TT * H;          // [T,H] fp32
  float* qkv      = x    + (long)TT * H;          // [T,QKVD] fp32
  float* tmpR     = qkv  + (long)TT * QKVD;       // [T,48]
  float* tmpO     = tmpR + (long)TT * 48;         // [T,16]
  float* pooled   = tmpO + (long)TT * 16;         // [B,H]
  float* zz       = pooled + (long)BB * H;        // [B,PH]
  float* biascat  = zz   + (long)BB * PH;         // [2,QKVD]
  float* bcat     = biascat + (long)NL * QKVD;    // [2,QKVD,16]
  float2* ropetab = (float2*)(bcat + (long)NL * QKVD * RR);  // [SS*64]
  float* endf32   = (float*)(ropetab + SS * 64);
  __hip_bfloat16* x_bf  = (__hip_bfloat16*)endf32;            // [T,H]
  __hip_bfloat16* ffbf  = x_bf + (long)TT * H;                // [T,FF]
  __hip_bfloat16* wgbf  = ffbf + (long)TT * FF;               // [FF,H]  Wg
  __hip_bfloat16* wubf  = wgbf + (long)FF * H;                // [FF,H]  Wu
  __hip_bfloat16* wdbf  = wubf + (long)FF * H;                // [H,FF]  Wd
  __hip_bfloat16* wqbf  = wdbf + (long)FF * H;                // [QKVD,H] qkv cat
  __hip_bfloat16* wobf  = wqbf + (long)QKVD * H;              // [H,H]   Wo
  size_t need_bf = (size_t)((char*)(wobf + (long)H * H) - (char*)d_ws);
  bool bfw = ws_size >= need_bf;

  k_embed<<<TT, 256, 0, stream>>>(ids, embed, h);
  k_rope_tab<<<(SS * 64 + 255) / 256, 256, 0, stream>>>(ropetab);
  k_prep<<<(NL * QKVD + 255) / 256, 256, 0, stream>>>(bq, bk, bv, Bq, Bk, Bv, biascat, bcat);

  for (int l = 0; l < NL; ++l) {
    const long lHH = (long)l * H * H;
    const long lKH = (long)l * KVD * H;
    const long lRH = (long)l * RR * H;
    const long lFH = (long)l * FF * H;
    // x,x_bf = rms(h, ln1)
    k_rmsnorm<<<TT, 256, 0, stream>>>(h, ln1 + l * H, x, x_bf);
    // lora downs for q/k/v in one dispatch
    k_lora_down3<<<dim3(TT, 3), 256, 0, stream>>>(
        x, Aq + lRH, Ak + lRH, Av + lRH, tmpR, 48);
    if (bfw) {
      k_cvt_qkv<<<cvt_grid((long)QKVD * H), 256, 0, stream>>>(
          Wq + lHH, Wk + lKH, Wv + lKH, wqbf);
      k_mgemm<ME_BIAS_F32, true, true><<<(TT / 64) * (QKVD / 128), 256, 0, stream>>>(
          x_bf, nullptr, nullptr, nullptr, wqbf, biascat + (long)l * QKVD, qkv,
          tmpR, bcat + (long)l * QKVD * RR, 48, 1, TT, QKVD, H);
    } else {
      k_mgemm<ME_BIAS_F32, true, false><<<(TT / 64) * (QKVD / 128), 256, 0, stream>>>(
          x_bf, Wq + lHH, Wk + lKH, Wv + lKH, nullptr, biascat + (long)l * QKVD, qkv,
          tmpR, bcat + (long)l * QKVD * RR, 48, 1, TT, QKVD, H);
    }
    // fused rope+attention (reads un-roped qkv, writes fp32 x and bf16 x_bf)
    k_attn2<<<dim3(BB, NKV, 4), 256, 0, stream>>>(qkv, mask, ropetab, x, x_bf);
    // h += attn @ Wo^T + lora
    k_lora_down3<<<dim3(TT, 1), 256, 0, stream>>>(
        x, Ao + lRH, Ao + lRH, Ao + lRH, tmpO, 16);
    if (bfw) {
      k_cvt<<<cvt_grid((long)H * H), 256, 0, stream>>>(Wo + lHH, wobf, (long)H * H);
      k_mgemm<ME_ACC_F32, true, true><<<(TT / 64) * (H / 128), 256, 0, stream>>>(
          x_bf, nullptr, nullptr, nullptr, wobf, nullptr, h,
          tmpO, Bo + (long)l * H * RR, 16, 0, TT, H, H);
    } else {
      k_mgemm<ME_ACC_F32, true, false><<<(TT / 64) * (H / 128), 256, 0, stream>>>(
          x_bf, Wo + lHH, Wo + lHH, Wo + lHH, nullptr, nullptr, h,
          tmpO, Bo + (long)l * H * RR, 16, 0, TT, H, H);
    }
    // MLP
    k_rmsnorm<<<TT, 256, 0, stream>>>(h, ln2 + l * H, x, x_bf);
    if (bfw) {
      k_cvt3<<<cvt_grid(3L * FF * H), 256, 0, stream>>>(
          Wg + lFH, Wu + lFH, Wd + lFH, wgbf);   // wgbf|wubf|wdbf contiguous
      k_swiglu_b<<<(TT / 128) * (FF / 128), 512, 0, stream>>>(
          x_bf, wgbf, wubf, ffbf, TT, FF, H);
      k_mgemm<ME_ACC_F32, false, true><<<(TT / 64) * (H / 128), 256, 0, stream>>>(
          ffbf, nullptr, nullptr, nullptr, wdbf, nullptr, h,
          nullptr, nullptr, 0, 0, TT, H, FF);
    } else {
      k_swiglu<<<(TT / 128) * (FF / 128), 256, 0, stream>>>(
          x_bf, Wg + lFH, Wu + lFH, ffbf, TT, FF, H);
      k_mgemm<ME_ACC_F32, false, false><<<(TT / 64) * (H / 128), 256, 0, stream>>>(
          ffbf, Wd + lFH, Wd + lFH, Wd + lFH, nullptr, nullptr, h,
          nullptr, nullptr, 0, 0, TT, H, FF);
    }
  }

  // final norm, pool, head (wave-per-output dot GEMMs)
  k_rmsnorm<<<TT, 256, 0, stream>>>(h, norm_f, x, x_bf);
  k_pool<<<BB, 256, 0, stream>>>(x, mask, pooled);
  k_hgemm<true><<<(BB * PH + 3) / 4, 256, 0, stream>>>(pooled, W1, b1, zz, BB, PH, H);
  k_hgemm<false><<<(BB * TDm + 3) / 4, 256, 0, stream>>>(zz, W2, b2, (float*)d_out, BB, TDm, PH);
}